// Round 12
// baseline (270.210 us; speedup 1.0000x reference)
//
#include <hip/hip_runtime.h>
#include <cstddef>
#include <cstdint>

// Problem constants
static constexpr int BB   = 2;
static constexpr int SS   = 384;
static constexpr int HH   = 768;
static constexpr int NHD  = 12;
static constexpr int ROWS = BB * SS;       // 768
#define SCALE_F 0.125f                     // 1/sqrt(64)

typedef __attribute__((ext_vector_type(8))) short short8;
typedef __attribute__((ext_vector_type(4))) float f32x4;

static __device__ __forceinline__ unsigned short f2bf(float x) {
    unsigned int b = __float_as_uint(x);
    b = (b + 0x7fffu + ((b >> 16) & 1u)) >> 16;   // round-to-nearest-even
    return (unsigned short)b;
}
static __device__ __forceinline__ float bf2f(unsigned short u) {
    return __uint_as_float((unsigned int)u << 16);
}

// ---------------------------------------------------------------------------
// fp32 -> bf16 converter (z<5: hs, Wq, Wk, Wv, Wf) + Wr transpose (z==5).
// grid (576, 6), block 256.
// ---------------------------------------------------------------------------
__global__ __launch_bounds__(256) void k_tobf(const float* __restrict__ s0,
                                              const float* __restrict__ s1,
                                              const float* __restrict__ s2,
                                              const float* __restrict__ s3,
                                              const float* __restrict__ s4,
                                              const float* __restrict__ Wr,
                                              unsigned short* __restrict__ d0,
                                              unsigned short* __restrict__ d1,
                                              unsigned short* __restrict__ d2,
                                              unsigned short* __restrict__ d3,
                                              unsigned short* __restrict__ d4,
                                              unsigned short* __restrict__ WrT) {
    __shared__ float t[32][33];
    const int z = blockIdx.y;
    if (z < 5) {
        const float* s = (z == 0) ? s0 : (z == 1) ? s1 : (z == 2) ? s2 : (z == 3) ? s3 : s4;
        unsigned short* d = (z == 0) ? d0 : (z == 1) ? d1 : (z == 2) ? d2 : (z == 3) ? d3 : d4;
        const int tt = blockIdx.x * 256 + threadIdx.x;      // < 147456
        const float4 v = *(const float4*)&s[(size_t)tt * 4];
        ushort4 o;
        o.x = f2bf(v.x); o.y = f2bf(v.y); o.z = f2bf(v.z); o.w = f2bf(v.w);
        *(ushort4*)&d[(size_t)tt * 4] = o;
    } else {
        // WrT[e][c] = Wr[c][e]  (bf16), 32x32 tiles, 24x24 tiles total
        const int tile = blockIdx.x;
        const int tr_ = tile / 24, tc_ = tile % 24;
        const int r = threadIdx.x >> 3, c4 = (threadIdx.x & 7) * 4;
        const float4 v = *(const float4*)&Wr[(size_t)(tr_ * 32 + r) * HH + tc_ * 32 + c4];
        t[r][c4 + 0] = v.x; t[r][c4 + 1] = v.y; t[r][c4 + 2] = v.z; t[r][c4 + 3] = v.w;
        __syncthreads();
        ushort4 o;
        o.x = f2bf(t[c4 + 0][r]); o.y = f2bf(t[c4 + 1][r]);
        o.z = f2bf(t[c4 + 2][r]); o.w = f2bf(t[c4 + 3][r]);
        *(ushort4*)&WrT[(size_t)(tc_ * 32 + r) * HH + tr_ * 32 + c4] = o;
    }
}

// ---------------------------------------------------------------------------
// qkv MFMA GEMM (no LDS): per z, C = hs @ W.T + b, emitted as bf16 operands:
//  z==0: qu_b = bf16(q + u_flat), qv_b = bf16(q + v_flat)
//  z==1: k_b  = bf16(k)
//  z==2: vT_b = bf16(v) stored transposed per head: [(b*NHD+h)*64+d][j]
// grid (12,12,3), block 256. Verified frag layout (m89/m91, R7/R8-proven).
// ---------------------------------------------------------------------------
__global__ __launch_bounds__(256) void k_gemm_qkv(const unsigned short* __restrict__ A,
                                                  const unsigned short* __restrict__ Wqb, const float* __restrict__ bq,
                                                  const unsigned short* __restrict__ Wkb, const float* __restrict__ bk,
                                                  const unsigned short* __restrict__ Wvb, const float* __restrict__ bv,
                                                  const float* __restrict__ uvec,
                                                  const float* __restrict__ vvec,
                                                  unsigned short* __restrict__ qu_b,
                                                  unsigned short* __restrict__ qv_b,
                                                  unsigned short* __restrict__ k_b,
                                                  unsigned short* __restrict__ vT_b) {
    const int z = blockIdx.z;
    const unsigned short* W = (z == 0) ? Wqb : (z == 1) ? Wkb : Wvb;
    const float* bias = (z == 0) ? bq : (z == 1) ? bk : bv;

    const int tid = threadIdx.x;
    const int wid = tid >> 6, lane = tid & 63;
    const int i0 = blockIdx.y * 64, o0 = blockIdx.x * 64;
    const int wr = (wid >> 1) * 32, wc = (wid & 1) * 32;
    const int lrow = lane & 15;
    const int kgrp = (lane >> 4) * 8;

    const unsigned short* Ar0 = A + (size_t)(i0 + wr + lrow) * HH + kgrp;
    const unsigned short* Ar1 = Ar0 + 16 * HH;
    const unsigned short* Wr0 = W + (size_t)(o0 + wc + lrow) * HH + kgrp;
    const unsigned short* Wr1 = Wr0 + 16 * HH;

    f32x4 acc00 = {0.f,0.f,0.f,0.f}, acc01 = {0.f,0.f,0.f,0.f};
    f32x4 acc10 = {0.f,0.f,0.f,0.f}, acc11 = {0.f,0.f,0.f,0.f};
#pragma unroll 4
    for (int k0 = 0; k0 < HH; k0 += 32) {
        const short8 a0 = *(const short8*)(Ar0 + k0);
        const short8 a1 = *(const short8*)(Ar1 + k0);
        const short8 b0 = *(const short8*)(Wr0 + k0);
        const short8 b1 = *(const short8*)(Wr1 + k0);
        acc00 = __builtin_amdgcn_mfma_f32_16x16x32_bf16(a0, b0, acc00, 0, 0, 0);
        acc01 = __builtin_amdgcn_mfma_f32_16x16x32_bf16(a0, b1, acc01, 0, 0, 0);
        acc10 = __builtin_amdgcn_mfma_f32_16x16x32_bf16(a1, b0, acc10, 0, 0, 0);
        acc11 = __builtin_amdgcn_mfma_f32_16x16x32_bf16(a1, b1, acc11, 0, 0, 0);
    }

    const int rbase = (lane >> 4) * 4;
#pragma unroll
    for (int tr = 0; tr < 2; tr++) {
#pragma unroll
        for (int tc = 0; tc < 2; tc++) {
            const f32x4 a = (tr == 0) ? ((tc == 0) ? acc00 : acc01)
                                      : ((tc == 0) ? acc10 : acc11);
            const int col = o0 + wc + tc * 16 + lrow;
            const float bvv = bias[col];
            if (z == 0) {
                const float uu = uvec[col], vv = vvec[col];
#pragma unroll
                for (int r = 0; r < 4; r++) {
                    const int row = i0 + wr + tr * 16 + rbase + r;
                    const float val = a[r] + bvv;
                    qu_b[(size_t)row * HH + col] = f2bf(val + uu);
                    qv_b[(size_t)row * HH + col] = f2bf(val + vv);
                }
            } else if (z == 1) {
#pragma unroll
                for (int r = 0; r < 4; r++) {
                    const int row = i0 + wr + tr * 16 + rbase + r;
                    k_b[(size_t)row * HH + col] = f2bf(a[r] + bvv);
                }
            } else {
                const int row0 = i0 + wr + tr * 16 + rbase;
                const int bb2 = row0 / SS;
                const int jj0 = row0 - bb2 * SS;
                const int h2 = col >> 6, d2 = col & 63;
                ushort4 o;
                o.x = f2bf(a[0] + bvv); o.y = f2bf(a[1] + bvv);
                o.z = f2bf(a[2] + bvv); o.w = f2bf(a[3] + bvv);
                *(ushort4*)&vT_b[((size_t)(bb2 * NHD + h2) * 64 + d2) * SS + jj0] = o;
            }
        }
    }
}

// ---------------------------------------------------------------------------
// Merged middle kernel (one launch, range dispatch over 2592 blocks):
//  [0, 1728):    uproj  U[row,h,e] = sum_d qv_b[row,hd] * WrT[e,hd]  (K=64 MFMA)
//  [1728, 2592): ac     sc[b,i,h,j] = qu.k (K=64 MFMA) + cb (computed in-block)
// ---------------------------------------------------------------------------
__global__ __launch_bounds__(256) void k_mid(const unsigned short* __restrict__ qv,
                                             const unsigned short* __restrict__ WrT,
                                             const unsigned short* __restrict__ qu,
                                             const unsigned short* __restrict__ kb,
                                             const float* __restrict__ br,
                                             unsigned short* __restrict__ U,
                                             float* __restrict__ sc) {
    __shared__ float cbl[64];
    const int bx = blockIdx.x;
    const int tid = threadIdx.x;
    const int wid = tid >> 6, lane = tid & 63;
    const int wr = (wid >> 1) * 32, wc = (wid & 1) * 32;
    const int lrow = lane & 15;
    const int kgrp = (lane >> 4) * 8;
    const int rbase = (lane >> 4) * 4;

    if (bx < 1728) {
        // ------------- uproj -------------
        const int h = bx / 144;
        const int r0 = ((bx / 12) % 12) * 64, e0 = (bx % 12) * 64;

        const unsigned short* Ar0 = qv + (size_t)(r0 + wr + lrow) * HH + h * 64 + kgrp;
        const unsigned short* Ar1 = Ar0 + 16 * HH;
        const unsigned short* Br0 = WrT + (size_t)(e0 + wc + lrow) * HH + h * 64 + kgrp;
        const unsigned short* Br1 = Br0 + 16 * HH;

        f32x4 acc00 = {0.f,0.f,0.f,0.f}, acc01 = {0.f,0.f,0.f,0.f};
        f32x4 acc10 = {0.f,0.f,0.f,0.f}, acc11 = {0.f,0.f,0.f,0.f};
#pragma unroll
        for (int k0 = 0; k0 < 64; k0 += 32) {
            const short8 a0 = *(const short8*)(Ar0 + k0);
            const short8 a1 = *(const short8*)(Ar1 + k0);
            const short8 b0 = *(const short8*)(Br0 + k0);
            const short8 b1 = *(const short8*)(Br1 + k0);
            acc00 = __builtin_amdgcn_mfma_f32_16x16x32_bf16(a0, b0, acc00, 0, 0, 0);
            acc01 = __builtin_amdgcn_mfma_f32_16x16x32_bf16(a0, b1, acc01, 0, 0, 0);
            acc10 = __builtin_amdgcn_mfma_f32_16x16x32_bf16(a1, b0, acc10, 0, 0, 0);
            acc11 = __builtin_amdgcn_mfma_f32_16x16x32_bf16(a1, b1, acc11, 0, 0, 0);
        }
#pragma unroll
        for (int tr = 0; tr < 2; tr++) {
#pragma unroll
            for (int tc = 0; tc < 2; tc++) {
                const f32x4 a = (tr == 0) ? ((tc == 0) ? acc00 : acc01)
                                          : ((tc == 0) ? acc10 : acc11);
                const int e = e0 + wc + tc * 16 + lrow;
#pragma unroll
                for (int r = 0; r < 4; r++) {
                    const int row = r0 + wr + tr * 16 + rbase + r;
                    U[(size_t)row * (NHD * HH) + (size_t)h * HH + e] = f2bf(a[r]);
                }
            }
        }
    } else {
        // ------------- ac (+in-block cb) -------------
        const int idx = bx - 1728;
        const int j0 = (idx % 6) * 64, i0 = ((idx / 6) % 6) * 64;
        const int bh = idx / 36;
        const int b = bh / NHD, h = bh - b * NHD;

        // cb[r] = sum_d qv[(b,i0+r), h*64+d] * br[h*64+d]
        {
            const int r = tid >> 2, seg = tid & 3;
            const unsigned short* qrow = qv + (size_t)(b * SS + i0 + r) * HH + h * 64 + seg * 16;
            const float* brp = br + h * 64 + seg * 16;
            float p = 0.f;
#pragma unroll
            for (int d = 0; d < 16; d++)
                p = fmaf(bf2f(qrow[d]), brp[d], p);
            p += __shfl_xor(p, 1);
            p += __shfl_xor(p, 2);
            if (seg == 0) cbl[r] = p;
        }
        __syncthreads();

        const unsigned short* Ar0 = qu + (size_t)(b * SS + i0 + wr + lrow) * HH + h * 64 + kgrp;
        const unsigned short* Ar1 = Ar0 + 16 * HH;
        const unsigned short* Br0 = kb + (size_t)(b * SS + j0 + wc + lrow) * HH + h * 64 + kgrp;
        const unsigned short* Br1 = Br0 + 16 * HH;

        f32x4 acc00 = {0.f,0.f,0.f,0.f}, acc01 = {0.f,0.f,0.f,0.f};
        f32x4 acc10 = {0.f,0.f,0.f,0.f}, acc11 = {0.f,0.f,0.f,0.f};
#pragma unroll
        for (int k0 = 0; k0 < 64; k0 += 32) {
            const short8 a0 = *(const short8*)(Ar0 + k0);
            const short8 a1 = *(const short8*)(Ar1 + k0);
            const short8 b0 = *(const short8*)(Br0 + k0);
            const short8 b1 = *(const short8*)(Br1 + k0);
            acc00 = __builtin_amdgcn_mfma_f32_16x16x32_bf16(a0, b0, acc00, 0, 0, 0);
            acc01 = __builtin_amdgcn_mfma_f32_16x16x32_bf16(a0, b1, acc01, 0, 0, 0);
            acc10 = __builtin_amdgcn_mfma_f32_16x16x32_bf16(a1, b0, acc10, 0, 0, 0);
            acc11 = __builtin_amdgcn_mfma_f32_16x16x32_bf16(a1, b1, acc11, 0, 0, 0);
        }
#pragma unroll
        for (int tr = 0; tr < 2; tr++) {
#pragma unroll
            for (int tc = 0; tc < 2; tc++) {
                const f32x4 a = (tr == 0) ? ((tc == 0) ? acc00 : acc01)
                                          : ((tc == 0) ? acc10 : acc11);
                const int j = j0 + wc + tc * 16 + lrow;
#pragma unroll
                for (int r = 0; r < 4; r++) {
                    const int ii = i0 + wr + tr * 16 + rbase + r;
                    sc[((size_t)(b * SS + ii) * NHD + h) * SS + j] = a[r] + cbl[ii - i0];
                }
            }
        }
    }
}

// ---------------------------------------------------------------------------
// BD + softmax: one block per (b,i), 384 threads (6 waves), U in bf16 LDS.
// R12 experiment: 6 waves/block (R2's decomposition) at unchanged R8 lane
// mapping -> 18 waves/CU (vs 12) for more in-flight memory requests.
// No launch_bounds min-waves hint (R4 spill lesson). LDS 37.9 KB: 3 blocks/CU
// co-resident if VGPR <= ~102.
// ---------------------------------------------------------------------------
__global__ __launch_bounds__(384) void k_bd(const float* __restrict__ rpe,
                                            const unsigned short* __restrict__ U,
                                            const int* __restrict__ mask,
                                            const float* __restrict__ scin,
                                            unsigned short* __restrict__ Pb) {
    const int i = blockIdx.x;          // 0..383
    const int b = blockIdx.y;          // 0..1
    const int row = b * SS + i;
    const int tid = threadIdx.x;

    __shared__ unsigned short Ul[NHD * HH];   // 18 KB (bf16)
    __shared__ float sc[NHD][392];            // 18.4 KB
    __shared__ float extl[SS];                // 1.5 KB

    const float* plane = scin + (size_t)row * NHD * SS;
    unsigned short* pplane = Pb + (size_t)row * NHD * SS;

    // stage U row (bf16), AC scores plane, mask
    {
        const uint4* Ur = (const uint4*)(U + (size_t)row * NHD * HH);
        uint4* Uld = (uint4*)Ul;
        for (int t = tid; t < NHD * HH / 8; t += 384) Uld[t] = Ur[t];
        for (int t = tid; t < NHD * 96; t += 384) {
            const int h = t / 96, c4 = (t - h * 96) << 2;
            *(float4*)&sc[h][c4] = *(const float4*)&plane[h * SS + c4];
        }
        if (tid < SS) extl[tid] = (1.0f - (float)mask[b * SS + tid]) * (-1e18f);
    }
    __syncthreads();

    const int wave = tid >> 6;       // 0..5
    const int lane = tid & 63;

    // ---- BD phase: stream rpe[b,i,:,:] once (R8 mapping, 2 groups/wave) ----
    {
        const int jsub = lane >> 3;      // 0..7
        const int elane = lane & 7;      // 0..7
        const float* rrow = rpe + (size_t)row * SS * HH;

        for (int g = wave; g < 12; g += 6) {
            const int jbase = g * 32 + jsub;
            const float* rp0 = rrow + (size_t)jbase * HH + (elane << 2);
            float acc[4][NHD] = {};
#pragma unroll 2
            for (int ec = 0; ec < 24; ec++) {
                const int eo = ec << 5;                 // 32 e per chunk
                const float4 t0 = *(const float4*)(rp0 + eo);
                const float4 t1 = *(const float4*)(rp0 + eo + 8 * HH);
                const float4 t2 = *(const float4*)(rp0 + eo + 16 * HH);
                const float4 t3 = *(const float4*)(rp0 + eo + 24 * HH);
                const float rb[4][4] = {{t0.x, t0.y, t0.z, t0.w},
                                        {t1.x, t1.y, t1.z, t1.w},
                                        {t2.x, t2.y, t2.z, t2.w},
                                        {t3.x, t3.y, t3.z, t3.w}};
                const int uo = eo + (elane << 2);       // ushort index, 8B aligned
#pragma unroll
                for (int h = 0; h < NHD; h++) {
                    const uint2 w2 = *(const uint2*)&Ul[h * HH + uo];
                    float ub[4];
                    ub[0] = __uint_as_float(w2.x << 16);
                    ub[1] = __uint_as_float(w2.x & 0xffff0000u);
                    ub[2] = __uint_as_float(w2.y << 16);
                    ub[3] = __uint_as_float(w2.y & 0xffff0000u);
#pragma unroll
                    for (int rr = 0; rr < 4; rr++)
#pragma unroll
                        for (int c = 0; c < 4; c++)
                            acc[rr][h] = fmaf(rb[rr][c], ub[c], acc[rr][h]);
                }
            }
#pragma unroll
            for (int rr = 0; rr < 4; rr++)
#pragma unroll
                for (int h = 0; h < NHD; h++) {
                    float a = acc[rr][h];
                    a += __shfl_xor(a, 1);
                    a += __shfl_xor(a, 2);
                    a += __shfl_xor(a, 4);
                    acc[rr][h] = a;
                }
            if (elane == 0) {
#pragma unroll
                for (int rr = 0; rr < 4; rr++) {
                    const int j = jbase + (rr << 3);
#pragma unroll
                    for (int h = 0; h < NHD; h++)
                        sc[h][j] += acc[rr][h];
                }
            }
        }
    }
    __syncthreads();

    // ---- fused softmax (scale + mask), write P (bf16), 2 heads/wave ----
    {
        for (int h = wave; h < NHD; h += 6) {
            float vbuf[6];
            float m = -1e30f;
#pragma unroll
            for (int t2 = 0; t2 < 6; t2++) {
                vbuf[t2] = sc[h][lane + t2 * 64] * SCALE_F + extl[lane + t2 * 64];
                m = fmaxf(m, vbuf[t2]);
            }
#pragma unroll
            for (int off = 1; off < 64; off <<= 1) m = fmaxf(m, __shfl_xor(m, off));
            float ssum = 0.f;
#pragma unroll
            for (int t2 = 0; t2 < 6; t2++) {
                const float e = __expf(vbuf[t2] - m);
                vbuf[t2] = e;
                ssum += e;
            }
#pragma unroll
            for (int off = 1; off < 64; off <<= 1) ssum += __shfl_xor(ssum, off);
            const float inv = 1.0f / ssum;
#pragma unroll
            for (int t2 = 0; t2 < 6; t2++)
                pplane[h * SS + lane + t2 * 64] = f2bf(vbuf[t2] * inv);
        }
    }
}

// ---------------------------------------------------------------------------
// PV MFMA: ctx_b[b,i,h*64+d] = sum_j P_b[b,i,h,j] * vT_b[(b,h,d),j]  (bf16 out)
// grid (6 itile, 24 bh), block 256, K=384.
// ---------------------------------------------------------------------------
__global__ __launch_bounds__(256) void k_pv(const unsigned short* __restrict__ Pb,
                                            const unsigned short* __restrict__ vTb,
                                            unsigned short* __restrict__ ctxb) {
    const int bh = blockIdx.y;
    const int b = bh / NHD, h = bh - b * NHD;
    const int i0 = blockIdx.x * 64;
    const int tid = threadIdx.x;
    const int wid = tid >> 6, lane = tid & 63;
    const int wr = (wid >> 1) * 32, wc = (wid & 1) * 32;
    const int lrow = lane & 15;
    const int kgrp = (lane >> 4) * 8;

    const unsigned short* Ar0 = Pb + ((size_t)(b * SS + i0 + wr + lrow) * NHD + h) * SS + kgrp;
    const unsigned short* Ar1 = Ar0 + (size_t)16 * NHD * SS;
    const unsigned short* Br0 = vTb + ((size_t)(b * NHD + h) * 64 + wc + lrow) * SS + kgrp;
    const unsigned short* Br1 = Br0 + 16 * SS;

    f32x4 acc00 = {0.f,0.f,0.f,0.f}, acc01 = {0.f,0.f,0.f,0.f};
    f32x4 acc10 = {0.f,0.f,0.f,0.f}, acc11 = {0.f,0.f,0.f,0.f};
#pragma unroll 4
    for (int k0 = 0; k0 < SS; k0 += 32) {
        const short8 a0 = *(const short8*)(Ar0 + k0);
        const short8 a1 = *(const short8*)(Ar1 + k0);
        const short8 b0 = *(const short8*)(Br0 + k0);
        const short8 b1 = *(const short8*)(Br1 + k0);
        acc00 = __builtin_amdgcn_mfma_f32_16x16x32_bf16(a0, b0, acc00, 0, 0, 0);
        acc01 = __builtin_amdgcn_mfma_f32_16x16x32_bf16(a0, b1, acc01, 0, 0, 0);
        acc10 = __builtin_amdgcn_mfma_f32_16x16x32_bf16(a1, b0, acc10, 0, 0, 0);
        acc11 = __builtin_amdgcn_mfma_f32_16x16x32_bf16(a1, b1, acc11, 0, 0, 0);
    }

    const int rbase = (lane >> 4) * 4;
#pragma unroll
    for (int tr = 0; tr < 2; tr++) {
#pragma unroll
        for (int tc = 0; tc < 2; tc++) {
            const f32x4 a = (tr == 0) ? ((tc == 0) ? acc00 : acc01)
                                      : ((tc == 0) ? acc10 : acc11);
            const int d = wc + tc * 16 + lrow;
#pragma unroll
            for (int r = 0; r < 4; r++) {
                const int row = b * SS + i0 + wr + tr * 16 + rbase + r;
                ctxb[(size_t)row * HH + h * 64 + d] = f2bf(a[r]);
            }
        }
    }
}

// ---------------------------------------------------------------------------
// out-proj MFMA (R7-proven): lnin = ctx_b @ Wf_b.T + bf + hs
// ---------------------------------------------------------------------------
__global__ __launch_bounds__(256) void k_gemm_out(const unsigned short* __restrict__ A,
                                                  const unsigned short* __restrict__ W,
                                                  const float* __restrict__ bias,
                                                  const float* __restrict__ addsrc,
                                                  float* __restrict__ C) {
    const int tid = threadIdx.x;
    const int wid = tid >> 6, lane = tid & 63;
    const int i0 = blockIdx.y * 64, o0 = blockIdx.x * 64;
    const int wr = (wid >> 1) * 32, wc = (wid & 1) * 32;
    const int lrow = lane & 15;
    const int kgrp = (lane >> 4) * 8;

    const unsigned short* Ar0 = A + (size_t)(i0 + wr + lrow) * HH + kgrp;
    const unsigned short* Ar1 = Ar0 + 16 * HH;
    const unsigned short* Wr0 = W + (size_t)(o0 + wc + lrow) * HH + kgrp;
    const unsigned short* Wr1 = Wr0 + 16 * HH;

    f32x4 acc00 = {0.f,0.f,0.f,0.f}, acc01 = {0.f,0.f,0.f,0.f};
    f32x4 acc10 = {0.f,0.f,0.f,0.f}, acc11 = {0.f,0.f,0.f,0.f};
#pragma unroll 4
    for (int k0 = 0; k0 < HH; k0 += 32) {
        const short8 a0 = *(const short8*)(Ar0 + k0);
        const short8 a1 = *(const short8*)(Ar1 + k0);
        const short8 b0 = *(const short8*)(Wr0 + k0);
        const short8 b1 = *(const short8*)(Wr1 + k0);
        acc00 = __builtin_amdgcn_mfma_f32_16x16x32_bf16(a0, b0, acc00, 0, 0, 0);
        acc01 = __builtin_amdgcn_mfma_f32_16x16x32_bf16(a0, b1, acc01, 0, 0, 0);
        acc10 = __builtin_amdgcn_mfma_f32_16x16x32_bf16(a1, b0, acc10, 0, 0, 0);
        acc11 = __builtin_amdgcn_mfma_f32_16x16x32_bf16(a1, b1, acc11, 0, 0, 0);
    }

    const int rbase = (lane >> 4) * 4;
#pragma unroll
    for (int tr = 0; tr < 2; tr++) {
#pragma unroll
        for (int tc = 0; tc < 2; tc++) {
            const f32x4 a = (tr == 0) ? ((tc == 0) ? acc00 : acc01)
                                      : ((tc == 0) ? acc10 : acc11);
            const int col = o0 + wc + tc * 16 + lrow;
            const float bv = bias[col];
#pragma unroll
            for (int r = 0; r < 4; r++) {
                const int row = i0 + wr + tr * 16 + rbase + r;
                C[(size_t)row * HH + col] = a[r] + bv + addsrc[(size_t)row * HH + col];
            }
        }
    }
}

// ---------------------------------------------------------------------------
// LayerNorm over last dim (768) per row
// ---------------------------------------------------------------------------
__global__ __launch_bounds__(256) void k_ln(const float* __restrict__ x,
                                            const float* __restrict__ g,
                                            const float* __restrict__ bta,
                                            float* __restrict__ o) {
    const int row = blockIdx.x;
    const int tid = threadIdx.x;
    const float* xr = x + (size_t)row * HH;
    __shared__ float red[4];
    const float v0 = xr[tid], v1 = xr[tid + 256], v2 = xr[tid + 512];
    float s = v0 + v1 + v2;
#pragma unroll
    for (int off = 1; off < 64; off <<= 1) s += __shfl_xor(s, off);
    if ((tid & 63) == 0) red[tid >> 6] = s;
    __syncthreads();
    const float mean = (red[0] + red[1] + red[2] + red[3]) * (1.0f / 768.0f);
    const float d0 = v0 - mean, d1 = v1 - mean, d2 = v2 - mean;
    float sq = d0 * d0 + d1 * d1 + d2 * d2;
#pragma unroll
    for (int off = 1; off < 64; off <<= 1) sq += __shfl_xor(sq, off);
    __syncthreads();
    if ((tid & 63) == 0) red[tid >> 6] = sq;
    __syncthreads();
    const float var = (red[0] + red[1] + red[2] + red[3]) * (1.0f / 768.0f);
    const float inv = rsqrtf(var + 1e-6f);
    o[(size_t)row * HH + tid]       = d0 * inv * g[tid]       + bta[tid];
    o[(size_t)row * HH + tid + 256] = d1 * inv * g[tid + 256] + bta[tid + 256];
    o[(size_t)row * HH + tid + 512] = d2 * inv * g[tid + 512] + bta[tid + 512];
}

// ---------------------------------------------------------------------------
extern "C" void kernel_launch(void* const* d_in, const int* in_sizes, int n_in,
                              void* d_out, int out_size, void* d_ws, size_t ws_size,
                              hipStream_t stream) {
    (void)in_sizes; (void)n_in; (void)out_size; (void)ws_size;
    const float* hs   = (const float*)d_in[0];
    const int*   mask = (const int*)d_in[1];
    const float* rpe  = (const float*)d_in[2];
    const float* Wq = (const float*)d_in[3];  const float* bq = (const float*)d_in[4];
    const float* Wk = (const float*)d_in[5];  const float* bk = (const float*)d_in[6];
    const float* Wv = (const float*)d_in[7];  const float* bv = (const float*)d_in[8];
    const float* Wr = (const float*)d_in[9];  const float* br = (const float*)d_in[10];
    const float* u  = (const float*)d_in[11]; const float* v  = (const float*)d_in[12];
    const float* Wf = (const float*)d_in[13]; const float* bf = (const float*)d_in[14];
    const float* lng = (const float*)d_in[15]; const float* lnb = (const float*)d_in[16];
    float* out = (float*)d_out;

    const size_t MAT = (size_t)ROWS * HH;              // 589824
    float* wsf     = (float*)d_ws;
    float* lnin_ws = wsf;                              // fp32 region
    float* sc_ws   = lnin_ws + MAT;                    // ROWS*NHD*SS f32
    unsigned short* U_ws  = (unsigned short*)(sc_ws + (size_t)ROWS * NHD * SS);
    unsigned short* hs_b  = U_ws + (size_t)ROWS * NHD * HH;
    unsigned short* Wq_b  = hs_b + MAT;
    unsigned short* Wk_b  = Wq_b + MAT;
    unsigned short* Wv_b  = Wk_b + MAT;
    unsigned short* Wf_b  = Wv_b + MAT;
    unsigned short* WrT_b = Wf_b + MAT;
    unsigned short* qu_b  = WrT_b + MAT;
    unsigned short* qv_b  = qu_b + MAT;
    unsigned short* k_b   = qv_b + MAT;
    unsigned short* vT_b  = k_b + MAT;
    unsigned short* ctx_b = vT_b + MAT;
    unsigned short* P_b   = ctx_b + MAT;               // ROWS*NHD*SS bf16

    k_tobf<<<dim3(576, 6), 256, 0, stream>>>(hs, Wq, Wk, Wv, Wf, Wr,
                                             hs_b, Wq_b, Wk_b, Wv_b, Wf_b, WrT_b);
    k_gemm_qkv<<<dim3(12, 12, 3), 256, 0, stream>>>(hs_b, Wq_b, bq, Wk_b, bk, Wv_b, bv,
                                                    u, v, qu_b, qv_b, k_b, vT_b);
    k_mid<<<dim3(2592), 256, 0, stream>>>(qv_b, WrT_b, qu_b, k_b, br, U_ws, sc_ws);
    k_bd<<<dim3(SS, BB), 384, 0, stream>>>(rpe, U_ws, mask, sc_ws, P_b);
    k_pv<<<dim3(6, 24), 256, 0, stream>>>(P_b, vT_b, ctx_b);
    k_gemm_out<<<dim3(12, 12), 256, 0, stream>>>(ctx_b, Wf_b, bf, hs, lnin_ws);
    k_ln<<<dim3(768), 256, 0, stream>>>(lnin_ws, lng, lnb, out);
}

// Round 13
// 264.956 us; speedup vs baseline: 1.0198x; 1.0198x over previous
//
#include <hip/hip_runtime.h>
#include <cstddef>
#include <cstdint>

// Problem constants
static constexpr int BB   = 2;
static constexpr int SS   = 384;
static constexpr int HH   = 768;
static constexpr int NHD  = 12;
static constexpr int ROWS = BB * SS;       // 768
#define SCALE_F 0.125f                     // 1/sqrt(64)

typedef __attribute__((ext_vector_type(8))) short short8;
typedef __attribute__((ext_vector_type(4))) float f32x4;

static __device__ __forceinline__ unsigned short f2bf(float x) {
    unsigned int b = __float_as_uint(x);
    b = (b + 0x7fffu + ((b >> 16) & 1u)) >> 16;   // round-to-nearest-even
    return (unsigned short)b;
}
static __device__ __forceinline__ float bf2f(unsigned short u) {
    return __uint_as_float((unsigned int)u << 16);
}

// ---------------------------------------------------------------------------
// fp32 -> bf16 converter (z<5: hs, Wq, Wk, Wv, Wf) + Wr transpose (z==5).
// grid (576, 6), block 256.
// ---------------------------------------------------------------------------
__global__ __launch_bounds__(256) void k_tobf(const float* __restrict__ s0,
                                              const float* __restrict__ s1,
                                              const float* __restrict__ s2,
                                              const float* __restrict__ s3,
                                              const float* __restrict__ s4,
                                              const float* __restrict__ Wr,
                                              unsigned short* __restrict__ d0,
                                              unsigned short* __restrict__ d1,
                                              unsigned short* __restrict__ d2,
                                              unsigned short* __restrict__ d3,
                                              unsigned short* __restrict__ d4,
                                              unsigned short* __restrict__ WrT) {
    __shared__ float t[32][33];
    const int z = blockIdx.y;
    if (z < 5) {
        const float* s = (z == 0) ? s0 : (z == 1) ? s1 : (z == 2) ? s2 : (z == 3) ? s3 : s4;
        unsigned short* d = (z == 0) ? d0 : (z == 1) ? d1 : (z == 2) ? d2 : (z == 3) ? d3 : d4;
        const int tt = blockIdx.x * 256 + threadIdx.x;      // < 147456
        const float4 v = *(const float4*)&s[(size_t)tt * 4];
        ushort4 o;
        o.x = f2bf(v.x); o.y = f2bf(v.y); o.z = f2bf(v.z); o.w = f2bf(v.w);
        *(ushort4*)&d[(size_t)tt * 4] = o;
    } else {
        // WrT[e][c] = Wr[c][e]  (bf16), 32x32 tiles, 24x24 tiles total
        const int tile = blockIdx.x;
        const int tr_ = tile / 24, tc_ = tile % 24;
        const int r = threadIdx.x >> 3, c4 = (threadIdx.x & 7) * 4;
        const float4 v = *(const float4*)&Wr[(size_t)(tr_ * 32 + r) * HH + tc_ * 32 + c4];
        t[r][c4 + 0] = v.x; t[r][c4 + 1] = v.y; t[r][c4 + 2] = v.z; t[r][c4 + 3] = v.w;
        __syncthreads();
        ushort4 o;
        o.x = f2bf(t[c4 + 0][r]); o.y = f2bf(t[c4 + 1][r]);
        o.z = f2bf(t[c4 + 2][r]); o.w = f2bf(t[c4 + 3][r]);
        *(ushort4*)&WrT[(size_t)(tc_ * 32 + r) * HH + tr_ * 32 + c4] = o;
    }
}

// ---------------------------------------------------------------------------
// qkv MFMA GEMM, 32x64 tile (R13: better CU fill, 864 blocks = 3.4/CU).
// Per wave: 16 rows x 32 cols = 2 MFMA tiles.  Outputs as bf16 operands:
//  z==0: qu_b = bf16(q + u_flat), qv_b = bf16(q + v_flat)
//  z==1: k_b  = bf16(k)
//  z==2: vT_b = bf16(v) transposed per head: [(b*NHD+h)*64+d][j]
// grid (12, 24, 3), block 256.
// ---------------------------------------------------------------------------
__global__ __launch_bounds__(256) void k_gemm_qkv(const unsigned short* __restrict__ A,
                                                  const unsigned short* __restrict__ Wqb, const float* __restrict__ bq,
                                                  const unsigned short* __restrict__ Wkb, const float* __restrict__ bk,
                                                  const unsigned short* __restrict__ Wvb, const float* __restrict__ bv,
                                                  const float* __restrict__ uvec,
                                                  const float* __restrict__ vvec,
                                                  unsigned short* __restrict__ qu_b,
                                                  unsigned short* __restrict__ qv_b,
                                                  unsigned short* __restrict__ k_b,
                                                  unsigned short* __restrict__ vT_b) {
    const int z = blockIdx.z;
    const unsigned short* W = (z == 0) ? Wqb : (z == 1) ? Wkb : Wvb;
    const float* bias = (z == 0) ? bq : (z == 1) ? bk : bv;

    const int tid = threadIdx.x;
    const int wid = tid >> 6, lane = tid & 63;
    const int i0 = blockIdx.y * 32, o0 = blockIdx.x * 64;
    const int wr = (wid >> 1) * 16;    // 0 or 16
    const int wc = (wid & 1) * 32;     // 0 or 32
    const int lrow = lane & 15;
    const int kgrp = (lane >> 4) * 8;

    const unsigned short* Ar0 = A + (size_t)(i0 + wr + lrow) * HH + kgrp;
    const unsigned short* Wr0 = W + (size_t)(o0 + wc + lrow) * HH + kgrp;
    const unsigned short* Wr1 = Wr0 + 16 * HH;

    f32x4 acc0 = {0.f,0.f,0.f,0.f}, acc1 = {0.f,0.f,0.f,0.f};
#pragma unroll 4
    for (int k0 = 0; k0 < HH; k0 += 32) {
        const short8 a0 = *(const short8*)(Ar0 + k0);
        const short8 b0 = *(const short8*)(Wr0 + k0);
        const short8 b1 = *(const short8*)(Wr1 + k0);
        acc0 = __builtin_amdgcn_mfma_f32_16x16x32_bf16(a0, b0, acc0, 0, 0, 0);
        acc1 = __builtin_amdgcn_mfma_f32_16x16x32_bf16(a0, b1, acc1, 0, 0, 0);
    }

    const int rbase = (lane >> 4) * 4;
#pragma unroll
    for (int tc = 0; tc < 2; tc++) {
        const f32x4 a = (tc == 0) ? acc0 : acc1;
        const int col = o0 + wc + tc * 16 + lrow;
        const float bvv = bias[col];
        if (z == 0) {
            const float uu = uvec[col], vv = vvec[col];
#pragma unroll
            for (int r = 0; r < 4; r++) {
                const int row = i0 + wr + rbase + r;
                const float val = a[r] + bvv;
                qu_b[(size_t)row * HH + col] = f2bf(val + uu);
                qv_b[(size_t)row * HH + col] = f2bf(val + vv);
            }
        } else if (z == 1) {
#pragma unroll
            for (int r = 0; r < 4; r++) {
                const int row = i0 + wr + rbase + r;
                k_b[(size_t)row * HH + col] = f2bf(a[r] + bvv);
            }
        } else {
            const int row0 = i0 + wr + rbase;          // 32-aligned tiles: same b
            const int bb2 = row0 / SS;
            const int jj0 = row0 - bb2 * SS;
            const int h2 = col >> 6, d2 = col & 63;
            ushort4 o;
            o.x = f2bf(a[0] + bvv); o.y = f2bf(a[1] + bvv);
            o.z = f2bf(a[2] + bvv); o.w = f2bf(a[3] + bvv);
            *(ushort4*)&vT_b[((size_t)(bb2 * NHD + h2) * 64 + d2) * SS + jj0] = o;
        }
    }
}

// ---------------------------------------------------------------------------
// Merged middle kernel (one launch, range dispatch over 2592 blocks):
//  [0, 1728):    uproj  U[row,h,e] = sum_d qv_b[row,hd] * WrT[e,hd]  (K=64 MFMA)
//  [1728, 2592): ac     sc[b,i,h,j] = qu.k (K=64 MFMA) + cb (computed in-block)
// ---------------------------------------------------------------------------
__global__ __launch_bounds__(256) void k_mid(const unsigned short* __restrict__ qv,
                                             const unsigned short* __restrict__ WrT,
                                             const unsigned short* __restrict__ qu,
                                             const unsigned short* __restrict__ kb,
                                             const float* __restrict__ br,
                                             unsigned short* __restrict__ U,
                                             float* __restrict__ sc) {
    __shared__ float cbl[64];
    const int bx = blockIdx.x;
    const int tid = threadIdx.x;
    const int wid = tid >> 6, lane = tid & 63;
    const int wr = (wid >> 1) * 32, wc = (wid & 1) * 32;
    const int lrow = lane & 15;
    const int kgrp = (lane >> 4) * 8;
    const int rbase = (lane >> 4) * 4;

    if (bx < 1728) {
        // ------------- uproj -------------
        const int h = bx / 144;
        const int r0 = ((bx / 12) % 12) * 64, e0 = (bx % 12) * 64;

        const unsigned short* Ar0 = qv + (size_t)(r0 + wr + lrow) * HH + h * 64 + kgrp;
        const unsigned short* Ar1 = Ar0 + 16 * HH;
        const unsigned short* Br0 = WrT + (size_t)(e0 + wc + lrow) * HH + h * 64 + kgrp;
        const unsigned short* Br1 = Br0 + 16 * HH;

        f32x4 acc00 = {0.f,0.f,0.f,0.f}, acc01 = {0.f,0.f,0.f,0.f};
        f32x4 acc10 = {0.f,0.f,0.f,0.f}, acc11 = {0.f,0.f,0.f,0.f};
#pragma unroll
        for (int k0 = 0; k0 < 64; k0 += 32) {
            const short8 a0 = *(const short8*)(Ar0 + k0);
            const short8 a1 = *(const short8*)(Ar1 + k0);
            const short8 b0 = *(const short8*)(Br0 + k0);
            const short8 b1 = *(const short8*)(Br1 + k0);
            acc00 = __builtin_amdgcn_mfma_f32_16x16x32_bf16(a0, b0, acc00, 0, 0, 0);
            acc01 = __builtin_amdgcn_mfma_f32_16x16x32_bf16(a0, b1, acc01, 0, 0, 0);
            acc10 = __builtin_amdgcn_mfma_f32_16x16x32_bf16(a1, b0, acc10, 0, 0, 0);
            acc11 = __builtin_amdgcn_mfma_f32_16x16x32_bf16(a1, b1, acc11, 0, 0, 0);
        }
#pragma unroll
        for (int tr = 0; tr < 2; tr++) {
#pragma unroll
            for (int tc = 0; tc < 2; tc++) {
                const f32x4 a = (tr == 0) ? ((tc == 0) ? acc00 : acc01)
                                          : ((tc == 0) ? acc10 : acc11);
                const int e = e0 + wc + tc * 16 + lrow;
#pragma unroll
                for (int r = 0; r < 4; r++) {
                    const int row = r0 + wr + tr * 16 + rbase + r;
                    U[(size_t)row * (NHD * HH) + (size_t)h * HH + e] = f2bf(a[r]);
                }
            }
        }
    } else {
        // ------------- ac (+in-block cb) -------------
        const int idx = bx - 1728;
        const int j0 = (idx % 6) * 64, i0 = ((idx / 6) % 6) * 64;
        const int bh = idx / 36;
        const int b = bh / NHD, h = bh - b * NHD;

        // cb[r] = sum_d qv[(b,i0+r), h*64+d] * br[h*64+d]
        {
            const int r = tid >> 2, seg = tid & 3;
            const unsigned short* qrow = qv + (size_t)(b * SS + i0 + r) * HH + h * 64 + seg * 16;
            const float* brp = br + h * 64 + seg * 16;
            float p = 0.f;
#pragma unroll
            for (int d = 0; d < 16; d++)
                p = fmaf(bf2f(qrow[d]), brp[d], p);
            p += __shfl_xor(p, 1);
            p += __shfl_xor(p, 2);
            if (seg == 0) cbl[r] = p;
        }
        __syncthreads();

        const unsigned short* Ar0 = qu + (size_t)(b * SS + i0 + wr + lrow) * HH + h * 64 + kgrp;
        const unsigned short* Ar1 = Ar0 + 16 * HH;
        const unsigned short* Br0 = kb + (size_t)(b * SS + j0 + wc + lrow) * HH + h * 64 + kgrp;
        const unsigned short* Br1 = Br0 + 16 * HH;

        f32x4 acc00 = {0.f,0.f,0.f,0.f}, acc01 = {0.f,0.f,0.f,0.f};
        f32x4 acc10 = {0.f,0.f,0.f,0.f}, acc11 = {0.f,0.f,0.f,0.f};
#pragma unroll
        for (int k0 = 0; k0 < 64; k0 += 32) {
            const short8 a0 = *(const short8*)(Ar0 + k0);
            const short8 a1 = *(const short8*)(Ar1 + k0);
            const short8 b0 = *(const short8*)(Br0 + k0);
            const short8 b1 = *(const short8*)(Br1 + k0);
            acc00 = __builtin_amdgcn_mfma_f32_16x16x32_bf16(a0, b0, acc00, 0, 0, 0);
            acc01 = __builtin_amdgcn_mfma_f32_16x16x32_bf16(a0, b1, acc01, 0, 0, 0);
            acc10 = __builtin_amdgcn_mfma_f32_16x16x32_bf16(a1, b0, acc10, 0, 0, 0);
            acc11 = __builtin_amdgcn_mfma_f32_16x16x32_bf16(a1, b1, acc11, 0, 0, 0);
        }
#pragma unroll
        for (int tr = 0; tr < 2; tr++) {
#pragma unroll
            for (int tc = 0; tc < 2; tc++) {
                const f32x4 a = (tr == 0) ? ((tc == 0) ? acc00 : acc01)
                                          : ((tc == 0) ? acc10 : acc11);
                const int j = j0 + wc + tc * 16 + lrow;
#pragma unroll
                for (int r = 0; r < 4; r++) {
                    const int ii = i0 + wr + tr * 16 + rbase + r;
                    sc[((size_t)(b * SS + ii) * NHD + h) * SS + j] = a[r] + cbl[ii - i0];
                }
            }
        }
    }
}

// ---------------------------------------------------------------------------
// BD + softmax: one block per (b,i), 256 threads, U in bf16 LDS. [R10-proven:
// null/negative results for segment-size (R11) and occupancy (R12) probes —
// this config is the measured local optimum.]  Softmax writes P as bf16.
// ---------------------------------------------------------------------------
__global__ __launch_bounds__(256) void k_bd(const float* __restrict__ rpe,
                                            const unsigned short* __restrict__ U,
                                            const int* __restrict__ mask,
                                            const float* __restrict__ scin,
                                            unsigned short* __restrict__ Pb) {
    const int i = blockIdx.x;          // 0..383
    const int b = blockIdx.y;          // 0..1
    const int row = b * SS + i;
    const int tid = threadIdx.x;

    __shared__ unsigned short Ul[NHD * HH];   // 18 KB (bf16)
    __shared__ float sc[NHD][392];            // 18.4 KB
    __shared__ float extl[SS];                // 1.5 KB

    const float* plane = scin + (size_t)row * NHD * SS;
    unsigned short* pplane = Pb + (size_t)row * NHD * SS;

    // stage U row (bf16), AC scores plane, mask
    {
        const uint4* Ur = (const uint4*)(U + (size_t)row * NHD * HH);
        uint4* Uld = (uint4*)Ul;
        for (int t = tid; t < NHD * HH / 8; t += 256) Uld[t] = Ur[t];
        for (int t = tid; t < NHD * 96; t += 256) {
            const int h = t / 96, c4 = (t - h * 96) << 2;
            *(float4*)&sc[h][c4] = *(const float4*)&plane[h * SS + c4];
        }
        for (int t = tid; t < SS; t += 256)
            extl[t] = (1.0f - (float)mask[b * SS + t]) * (-1e18f);
    }
    __syncthreads();

    const int wave = tid >> 6;       // 0..3
    const int lane = tid & 63;

    // ---- BD phase: stream rpe[b,i,:,:] once ----
    {
        const int jsub = lane >> 3;      // 0..7
        const int elane = lane & 7;      // 0..7
        const float* rrow = rpe + (size_t)row * SS * HH;

        for (int g = wave; g < 12; g += 4) {
            const int jbase = g * 32 + jsub;
            const float* rp0 = rrow + (size_t)jbase * HH + (elane << 2);
            float acc[4][NHD] = {};
#pragma unroll 2
            for (int ec = 0; ec < 24; ec++) {
                const int eo = ec << 5;                 // 32 e per chunk
                const float4 t0 = *(const float4*)(rp0 + eo);
                const float4 t1 = *(const float4*)(rp0 + eo + 8 * HH);
                const float4 t2 = *(const float4*)(rp0 + eo + 16 * HH);
                const float4 t3 = *(const float4*)(rp0 + eo + 24 * HH);
                const float rb[4][4] = {{t0.x, t0.y, t0.z, t0.w},
                                        {t1.x, t1.y, t1.z, t1.w},
                                        {t2.x, t2.y, t2.z, t2.w},
                                        {t3.x, t3.y, t3.z, t3.w}};
                const int uo = eo + (elane << 2);       // ushort index, 8B aligned
#pragma unroll
                for (int h = 0; h < NHD; h++) {
                    const uint2 w2 = *(const uint2*)&Ul[h * HH + uo];
                    float ub[4];
                    ub[0] = __uint_as_float(w2.x << 16);
                    ub[1] = __uint_as_float(w2.x & 0xffff0000u);
                    ub[2] = __uint_as_float(w2.y << 16);
                    ub[3] = __uint_as_float(w2.y & 0xffff0000u);
#pragma unroll
                    for (int rr = 0; rr < 4; rr++)
#pragma unroll
                        for (int c = 0; c < 4; c++)
                            acc[rr][h] = fmaf(rb[rr][c], ub[c], acc[rr][h]);
                }
            }
#pragma unroll
            for (int rr = 0; rr < 4; rr++)
#pragma unroll
                for (int h = 0; h < NHD; h++) {
                    float a = acc[rr][h];
                    a += __shfl_xor(a, 1);
                    a += __shfl_xor(a, 2);
                    a += __shfl_xor(a, 4);
                    acc[rr][h] = a;
                }
            if (elane == 0) {
#pragma unroll
                for (int rr = 0; rr < 4; rr++) {
                    const int j = jbase + (rr << 3);
#pragma unroll
                    for (int h = 0; h < NHD; h++)
                        sc[h][j] += acc[rr][h];
                }
            }
        }
    }
    __syncthreads();

    // ---- fused softmax (scale + mask), write P (bf16) ----
    {
        for (int h = wave; h < NHD; h += 4) {
            float vbuf[6];
            float m = -1e30f;
#pragma unroll
            for (int t2 = 0; t2 < 6; t2++) {
                vbuf[t2] = sc[h][lane + t2 * 64] * SCALE_F + extl[lane + t2 * 64];
                m = fmaxf(m, vbuf[t2]);
            }
#pragma unroll
            for (int off = 1; off < 64; off <<= 1) m = fmaxf(m, __shfl_xor(m, off));
            float ssum = 0.f;
#pragma unroll
            for (int t2 = 0; t2 < 6; t2++) {
                const float e = __expf(vbuf[t2] - m);
                vbuf[t2] = e;
                ssum += e;
            }
#pragma unroll
            for (int off = 1; off < 64; off <<= 1) ssum += __shfl_xor(ssum, off);
            const float inv = 1.0f / ssum;
#pragma unroll
            for (int t2 = 0; t2 < 6; t2++)
                pplane[h * SS + lane + t2 * 64] = f2bf(vbuf[t2] * inv);
        }
    }
}

// ---------------------------------------------------------------------------
// PV MFMA: ctx_b[b,i,h*64+d] = sum_j P_b[b,i,h,j] * vT_b[(b,h,d),j]  (bf16 out)
// grid (6 itile, 24 bh), block 256, K=384.
// ---------------------------------------------------------------------------
__global__ __launch_bounds__(256) void k_pv(const unsigned short* __restrict__ Pb,
                                            const unsigned short* __restrict__ vTb,
                                            unsigned short* __restrict__ ctxb) {
    const int bh = blockIdx.y;
    const int b = bh / NHD, h = bh - b * NHD;
    const int i0 = blockIdx.x * 64;
    const int tid = threadIdx.x;
    const int wid = tid >> 6, lane = tid & 63;
    const int wr = (wid >> 1) * 32, wc = (wid & 1) * 32;
    const int lrow = lane & 15;
    const int kgrp = (lane >> 4) * 8;

    const unsigned short* Ar0 = Pb + ((size_t)(b * SS + i0 + wr + lrow) * NHD + h) * SS + kgrp;
    const unsigned short* Ar1 = Ar0 + (size_t)16 * NHD * SS;
    const unsigned short* Br0 = vTb + ((size_t)(b * NHD + h) * 64 + wc + lrow) * SS + kgrp;
    const unsigned short* Br1 = Br0 + 16 * SS;

    f32x4 acc00 = {0.f,0.f,0.f,0.f}, acc01 = {0.f,0.f,0.f,0.f};
    f32x4 acc10 = {0.f,0.f,0.f,0.f}, acc11 = {0.f,0.f,0.f,0.f};
#pragma unroll 4
    for (int k0 = 0; k0 < SS; k0 += 32) {
        const short8 a0 = *(const short8*)(Ar0 + k0);
        const short8 a1 = *(const short8*)(Ar1 + k0);
        const short8 b0 = *(const short8*)(Br0 + k0);
        const short8 b1 = *(const short8*)(Br1 + k0);
        acc00 = __builtin_amdgcn_mfma_f32_16x16x32_bf16(a0, b0, acc00, 0, 0, 0);
        acc01 = __builtin_amdgcn_mfma_f32_16x16x32_bf16(a0, b1, acc01, 0, 0, 0);
        acc10 = __builtin_amdgcn_mfma_f32_16x16x32_bf16(a1, b0, acc10, 0, 0, 0);
        acc11 = __builtin_amdgcn_mfma_f32_16x16x32_bf16(a1, b1, acc11, 0, 0, 0);
    }

    const int rbase = (lane >> 4) * 4;
#pragma unroll
    for (int tr = 0; tr < 2; tr++) {
#pragma unroll
        for (int tc = 0; tc < 2; tc++) {
            const f32x4 a = (tr == 0) ? ((tc == 0) ? acc00 : acc01)
                                      : ((tc == 0) ? acc10 : acc11);
            const int d = wc + tc * 16 + lrow;
#pragma unroll
            for (int r = 0; r < 4; r++) {
                const int row = b * SS + i0 + wr + tr * 16 + rbase + r;
                ctxb[(size_t)row * HH + h * 64 + d] = f2bf(a[r]);
            }
        }
    }
}

// ---------------------------------------------------------------------------
// out-proj MFMA, 32x64 tile (R13): lnin = ctx_b @ Wf_b.T + bf + hs
// grid (12, 24), block 256 -> 288 blocks.
// ---------------------------------------------------------------------------
__global__ __launch_bounds__(256) void k_gemm_out(const unsigned short* __restrict__ A,
                                                  const unsigned short* __restrict__ W,
                                                  const float* __restrict__ bias,
                                                  const float* __restrict__ addsrc,
                                                  float* __restrict__ C) {
    const int tid = threadIdx.x;
    const int wid = tid >> 6, lane = tid & 63;
    const int i0 = blockIdx.y * 32, o0 = blockIdx.x * 64;
    const int wr = (wid >> 1) * 16;    // 0 or 16
    const int wc = (wid & 1) * 32;     // 0 or 32
    const int lrow = lane & 15;
    const int kgrp = (lane >> 4) * 8;

    const unsigned short* Ar0 = A + (size_t)(i0 + wr + lrow) * HH + kgrp;
    const unsigned short* Wr0 = W + (size_t)(o0 + wc + lrow) * HH + kgrp;
    const unsigned short* Wr1 = Wr0 + 16 * HH;

    f32x4 acc0 = {0.f,0.f,0.f,0.f}, acc1 = {0.f,0.f,0.f,0.f};
#pragma unroll 4
    for (int k0 = 0; k0 < HH; k0 += 32) {
        const short8 a0 = *(const short8*)(Ar0 + k0);
        const short8 b0 = *(const short8*)(Wr0 + k0);
        const short8 b1 = *(const short8*)(Wr1 + k0);
        acc0 = __builtin_amdgcn_mfma_f32_16x16x32_bf16(a0, b0, acc0, 0, 0, 0);
        acc1 = __builtin_amdgcn_mfma_f32_16x16x32_bf16(a0, b1, acc1, 0, 0, 0);
    }

    const int rbase = (lane >> 4) * 4;
#pragma unroll
    for (int tc = 0; tc < 2; tc++) {
        const f32x4 a = (tc == 0) ? acc0 : acc1;
        const int col = o0 + wc + tc * 16 + lrow;
        const float bv = bias[col];
#pragma unroll
        for (int r = 0; r < 4; r++) {
            const int row = i0 + wr + rbase + r;
            C[(size_t)row * HH + col] = a[r] + bv + addsrc[(size_t)row * HH + col];
        }
    }
}

// ---------------------------------------------------------------------------
// LayerNorm over last dim (768) per row
// ---------------------------------------------------------------------------
__global__ __launch_bounds__(256) void k_ln(const float* __restrict__ x,
                                            const float* __restrict__ g,
                                            const float* __restrict__ bta,
                                            float* __restrict__ o) {
    const int row = blockIdx.x;
    const int tid = threadIdx.x;
    const float* xr = x + (size_t)row * HH;
    __shared__ float red[4];
    const float v0 = xr[tid], v1 = xr[tid + 256], v2 = xr[tid + 512];
    float s = v0 + v1 + v2;
#pragma unroll
    for (int off = 1; off < 64; off <<= 1) s += __shfl_xor(s, off);
    if ((tid & 63) == 0) red[tid >> 6] = s;
    __syncthreads();
    const float mean = (red[0] + red[1] + red[2] + red[3]) * (1.0f / 768.0f);
    const float d0 = v0 - mean, d1 = v1 - mean, d2 = v2 - mean;
    float sq = d0 * d0 + d1 * d1 + d2 * d2;
#pragma unroll
    for (int off = 1; off < 64; off <<= 1) sq += __shfl_xor(sq, off);
    __syncthreads();
    if ((tid & 63) == 0) red[tid >> 6] = sq;
    __syncthreads();
    const float var = (red[0] + red[1] + red[2] + red[3]) * (1.0f / 768.0f);
    const float inv = rsqrtf(var + 1e-6f);
    o[(size_t)row * HH + tid]       = d0 * inv * g[tid]       + bta[tid];
    o[(size_t)row * HH + tid + 256] = d1 * inv * g[tid + 256] + bta[tid + 256];
    o[(size_t)row * HH + tid + 512] = d2 * inv * g[tid + 512] + bta[tid + 512];
}

// ---------------------------------------------------------------------------
extern "C" void kernel_launch(void* const* d_in, const int* in_sizes, int n_in,
                              void* d_out, int out_size, void* d_ws, size_t ws_size,
                              hipStream_t stream) {
    (void)in_sizes; (void)n_in; (void)out_size; (void)ws_size;
    const float* hs   = (const float*)d_in[0];
    const int*   mask = (const int*)d_in[1];
    const float* rpe  = (const float*)d_in[2];
    const float* Wq = (const float*)d_in[3];  const float* bq = (const float*)d_in[4];
    const float* Wk = (const float*)d_in[5];  const float* bk = (const float*)d_in[6];
    const float* Wv = (const float*)d_in[7];  const float* bv = (const float*)d_in[8];
    const float* Wr = (const float*)d_in[9];  const float* br = (const float*)d_in[10];
    const float* u  = (const float*)d_in[11]; const float* v  = (const float*)d_in[12];
    const float* Wf = (const float*)d_in[13]; const float* bf = (const float*)d_in[14];
    const float* lng = (const float*)d_in[15]; const float* lnb = (const float*)d_in[16];
    float* out = (float*)d_out;

    const size_t MAT = (size_t)ROWS * HH;              // 589824
    float* wsf     = (float*)d_ws;
    float* lnin_ws = wsf;                              // fp32 region
    float* sc_ws   = lnin_ws + MAT;                    // ROWS*NHD*SS f32
    unsigned short* U_ws  = (unsigned short*)(sc_ws + (size_t)ROWS * NHD * SS);
    unsigned short* hs_b  = U_ws + (size_t)ROWS * NHD * HH;
    unsigned short* Wq_b  = hs_b + MAT;
    unsigned short* Wk_b  = Wq_b + MAT;
    unsigned short* Wv_b  = Wk_b + MAT;
    unsigned short* Wf_b  = Wv_b + MAT;
    unsigned short* WrT_b = Wf_b + MAT;
    unsigned short* qu_b  = WrT_b + MAT;
    unsigned short* qv_b  = qu_b + MAT;
    unsigned short* k_b   = qv_b + MAT;
    unsigned short* vT_b  = k_b + MAT;
    unsigned short* ctx_b = vT_b + MAT;
    unsigned short* P_b   = ctx_b + MAT;               // ROWS*NHD*SS bf16

    k_tobf<<<dim3(576, 6), 256, 0, stream>>>(hs, Wq, Wk, Wv, Wf, Wr,
                                             hs_b, Wq_b, Wk_b, Wv_b, Wf_b, WrT_b);
    k_gemm_qkv<<<dim3(12, 24, 3), 256, 0, stream>>>(hs_b, Wq_b, bq, Wk_b, bk, Wv_b, bv,
                                                    u, v, qu_b, qv_b, k_b, vT_b);
    k_mid<<<dim3(2592), 256, 0, stream>>>(qv_b, WrT_b, qu_b, k_b, br, U_ws, sc_ws);
    k_bd<<<dim3(SS, BB), 256, 0, stream>>>(rpe, U_ws, mask, sc_ws, P_b);
    k_pv<<<dim3(6, 24), 256, 0, stream>>>(P_b, vT_b, ctx_b);
    k_gemm_out<<<dim3(12, 24), 256, 0, stream>>>(ctx_b, Wf_b, bf, hs, lnin_ws);
    k_ln<<<dim3(768), 256, 0, stream>>>(lnin_ws, lng, lnb, out);
}

// Round 14
// 254.348 us; speedup vs baseline: 1.0624x; 1.0417x over previous
//
#include <hip/hip_runtime.h>
#include <cstddef>
#include <cstdint>

// Problem constants
static constexpr int BB   = 2;
static constexpr int SS   = 384;
static constexpr int HH   = 768;
static constexpr int NHD  = 12;
static constexpr int ROWS = BB * SS;       // 768
#define SCALE_F 0.125f                     // 1/sqrt(64)

typedef __attribute__((ext_vector_type(8))) short short8;
typedef __attribute__((ext_vector_type(4))) float f32x4;

static __device__ __forceinline__ unsigned short f2bf(float x) {
    unsigned int b = __float_as_uint(x);
    b = (b + 0x7fffu + ((b >> 16) & 1u)) >> 16;   // round-to-nearest-even
    return (unsigned short)b;
}
static __device__ __forceinline__ float bf2f(unsigned short u) {
    return __uint_as_float((unsigned int)u << 16);
}

// ---------------------------------------------------------------------------
// fp32 -> bf16 converter (z<5: hs, Wq, Wk, Wv, Wf) + Wr transpose (z==5).
// grid (576, 6), block 256.
// ---------------------------------------------------------------------------
__global__ __launch_bounds__(256) void k_tobf(const float* __restrict__ s0,
                                              const float* __restrict__ s1,
                                              const float* __restrict__ s2,
                                              const float* __restrict__ s3,
                                              const float* __restrict__ s4,
                                              const float* __restrict__ Wr,
                                              unsigned short* __restrict__ d0,
                                              unsigned short* __restrict__ d1,
                                              unsigned short* __restrict__ d2,
                                              unsigned short* __restrict__ d3,
                                              unsigned short* __restrict__ d4,
                                              unsigned short* __restrict__ WrT) {
    __shared__ float t[32][33];
    const int z = blockIdx.y;
    if (z < 5) {
        const float* s = (z == 0) ? s0 : (z == 1) ? s1 : (z == 2) ? s2 : (z == 3) ? s3 : s4;
        unsigned short* d = (z == 0) ? d0 : (z == 1) ? d1 : (z == 2) ? d2 : (z == 3) ? d3 : d4;
        const int tt = blockIdx.x * 256 + threadIdx.x;      // < 147456
        const float4 v = *(const float4*)&s[(size_t)tt * 4];
        ushort4 o;
        o.x = f2bf(v.x); o.y = f2bf(v.y); o.z = f2bf(v.z); o.w = f2bf(v.w);
        *(ushort4*)&d[(size_t)tt * 4] = o;
    } else {
        // WrT[e][c] = Wr[c][e]  (bf16), 32x32 tiles, 24x24 tiles total
        const int tile = blockIdx.x;
        const int tr_ = tile / 24, tc_ = tile % 24;
        const int r = threadIdx.x >> 3, c4 = (threadIdx.x & 7) * 4;
        const float4 v = *(const float4*)&Wr[(size_t)(tr_ * 32 + r) * HH + tc_ * 32 + c4];
        t[r][c4 + 0] = v.x; t[r][c4 + 1] = v.y; t[r][c4 + 2] = v.z; t[r][c4 + 3] = v.w;
        __syncthreads();
        ushort4 o;
        o.x = f2bf(t[c4 + 0][r]); o.y = f2bf(t[c4 + 1][r]);
        o.z = f2bf(t[c4 + 2][r]); o.w = f2bf(t[c4 + 3][r]);
        *(ushort4*)&WrT[(size_t)(tc_ * 32 + r) * HH + tr_ * 32 + c4] = o;
    }
}

// ---------------------------------------------------------------------------
// qkv MFMA GEMM (no LDS): per z, C = hs @ W.T + b, emitted as bf16 operands:
//  z==0: qu_b = bf16(q + u_flat), qv_b = bf16(q + v_flat)
//  z==1: k_b  = bf16(k)
//  z==2: vT_b = bf16(v) stored transposed per head: [(b*NHD+h)*64+d][j]
// grid (12,12,3), block 256. Verified frag layout (m89/m91, R7/R8-proven).
// [R13 probe: 32x64 retile cost ~10us (halved A-fragment reuse) — 64x64 kept]
// ---------------------------------------------------------------------------
__global__ __launch_bounds__(256) void k_gemm_qkv(const unsigned short* __restrict__ A,
                                                  const unsigned short* __restrict__ Wqb, const float* __restrict__ bq,
                                                  const unsigned short* __restrict__ Wkb, const float* __restrict__ bk,
                                                  const unsigned short* __restrict__ Wvb, const float* __restrict__ bv,
                                                  const float* __restrict__ uvec,
                                                  const float* __restrict__ vvec,
                                                  unsigned short* __restrict__ qu_b,
                                                  unsigned short* __restrict__ qv_b,
                                                  unsigned short* __restrict__ k_b,
                                                  unsigned short* __restrict__ vT_b) {
    const int z = blockIdx.z;
    const unsigned short* W = (z == 0) ? Wqb : (z == 1) ? Wkb : Wvb;
    const float* bias = (z == 0) ? bq : (z == 1) ? bk : bv;

    const int tid = threadIdx.x;
    const int wid = tid >> 6, lane = tid & 63;
    const int i0 = blockIdx.y * 64, o0 = blockIdx.x * 64;
    const int wr = (wid >> 1) * 32, wc = (wid & 1) * 32;
    const int lrow = lane & 15;
    const int kgrp = (lane >> 4) * 8;

    const unsigned short* Ar0 = A + (size_t)(i0 + wr + lrow) * HH + kgrp;
    const unsigned short* Ar1 = Ar0 + 16 * HH;
    const unsigned short* Wr0 = W + (size_t)(o0 + wc + lrow) * HH + kgrp;
    const unsigned short* Wr1 = Wr0 + 16 * HH;

    f32x4 acc00 = {0.f,0.f,0.f,0.f}, acc01 = {0.f,0.f,0.f,0.f};
    f32x4 acc10 = {0.f,0.f,0.f,0.f}, acc11 = {0.f,0.f,0.f,0.f};
#pragma unroll 4
    for (int k0 = 0; k0 < HH; k0 += 32) {
        const short8 a0 = *(const short8*)(Ar0 + k0);
        const short8 a1 = *(const short8*)(Ar1 + k0);
        const short8 b0 = *(const short8*)(Wr0 + k0);
        const short8 b1 = *(const short8*)(Wr1 + k0);
        acc00 = __builtin_amdgcn_mfma_f32_16x16x32_bf16(a0, b0, acc00, 0, 0, 0);
        acc01 = __builtin_amdgcn_mfma_f32_16x16x32_bf16(a0, b1, acc01, 0, 0, 0);
        acc10 = __builtin_amdgcn_mfma_f32_16x16x32_bf16(a1, b0, acc10, 0, 0, 0);
        acc11 = __builtin_amdgcn_mfma_f32_16x16x32_bf16(a1, b1, acc11, 0, 0, 0);
    }

    const int rbase = (lane >> 4) * 4;
#pragma unroll
    for (int tr = 0; tr < 2; tr++) {
#pragma unroll
        for (int tc = 0; tc < 2; tc++) {
            const f32x4 a = (tr == 0) ? ((tc == 0) ? acc00 : acc01)
                                      : ((tc == 0) ? acc10 : acc11);
            const int col = o0 + wc + tc * 16 + lrow;
            const float bvv = bias[col];
            if (z == 0) {
                const float uu = uvec[col], vv = vvec[col];
#pragma unroll
                for (int r = 0; r < 4; r++) {
                    const int row = i0 + wr + tr * 16 + rbase + r;
                    const float val = a[r] + bvv;
                    qu_b[(size_t)row * HH + col] = f2bf(val + uu);
                    qv_b[(size_t)row * HH + col] = f2bf(val + vv);
                }
            } else if (z == 1) {
#pragma unroll
                for (int r = 0; r < 4; r++) {
                    const int row = i0 + wr + tr * 16 + rbase + r;
                    k_b[(size_t)row * HH + col] = f2bf(a[r] + bvv);
                }
            } else {
                const int row0 = i0 + wr + tr * 16 + rbase;
                const int bb2 = row0 / SS;
                const int jj0 = row0 - bb2 * SS;
                const int h2 = col >> 6, d2 = col & 63;
                ushort4 o;
                o.x = f2bf(a[0] + bvv); o.y = f2bf(a[1] + bvv);
                o.z = f2bf(a[2] + bvv); o.w = f2bf(a[3] + bvv);
                *(ushort4*)&vT_b[((size_t)(bb2 * NHD + h2) * 64 + d2) * SS + jj0] = o;
            }
        }
    }
}

// ---------------------------------------------------------------------------
// Merged middle kernel (one launch, range dispatch over 2592 blocks):
//  [0, 1728):    uproj  U[row,h,e] = sum_d qv_b[row,hd] * WrT[e,hd]  (K=64 MFMA)
//  [1728, 2592): ac     sc[b,i,h,j] = qu.k (K=64 MFMA) + cb (computed in-block)
// ---------------------------------------------------------------------------
__global__ __launch_bounds__(256) void k_mid(const unsigned short* __restrict__ qv,
                                             const unsigned short* __restrict__ WrT,
                                             const unsigned short* __restrict__ qu,
                                             const unsigned short* __restrict__ kb,
                                             const float* __restrict__ br,
                                             unsigned short* __restrict__ U,
                                             float* __restrict__ sc) {
    __shared__ float cbl[64];
    const int bx = blockIdx.x;
    const int tid = threadIdx.x;
    const int wid = tid >> 6, lane = tid & 63;
    const int wr = (wid >> 1) * 32, wc = (wid & 1) * 32;
    const int lrow = lane & 15;
    const int kgrp = (lane >> 4) * 8;
    const int rbase = (lane >> 4) * 4;

    if (bx < 1728) {
        // ------------- uproj -------------
        const int h = bx / 144;
        const int r0 = ((bx / 12) % 12) * 64, e0 = (bx % 12) * 64;

        const unsigned short* Ar0 = qv + (size_t)(r0 + wr + lrow) * HH + h * 64 + kgrp;
        const unsigned short* Ar1 = Ar0 + 16 * HH;
        const unsigned short* Br0 = WrT + (size_t)(e0 + wc + lrow) * HH + h * 64 + kgrp;
        const unsigned short* Br1 = Br0 + 16 * HH;

        f32x4 acc00 = {0.f,0.f,0.f,0.f}, acc01 = {0.f,0.f,0.f,0.f};
        f32x4 acc10 = {0.f,0.f,0.f,0.f}, acc11 = {0.f,0.f,0.f,0.f};
#pragma unroll
        for (int k0 = 0; k0 < 64; k0 += 32) {
            const short8 a0 = *(const short8*)(Ar0 + k0);
            const short8 a1 = *(const short8*)(Ar1 + k0);
            const short8 b0 = *(const short8*)(Br0 + k0);
            const short8 b1 = *(const short8*)(Br1 + k0);
            acc00 = __builtin_amdgcn_mfma_f32_16x16x32_bf16(a0, b0, acc00, 0, 0, 0);
            acc01 = __builtin_amdgcn_mfma_f32_16x16x32_bf16(a0, b1, acc01, 0, 0, 0);
            acc10 = __builtin_amdgcn_mfma_f32_16x16x32_bf16(a1, b0, acc10, 0, 0, 0);
            acc11 = __builtin_amdgcn_mfma_f32_16x16x32_bf16(a1, b1, acc11, 0, 0, 0);
        }
#pragma unroll
        for (int tr = 0; tr < 2; tr++) {
#pragma unroll
            for (int tc = 0; tc < 2; tc++) {
                const f32x4 a = (tr == 0) ? ((tc == 0) ? acc00 : acc01)
                                          : ((tc == 0) ? acc10 : acc11);
                const int e = e0 + wc + tc * 16 + lrow;
#pragma unroll
                for (int r = 0; r < 4; r++) {
                    const int row = r0 + wr + tr * 16 + rbase + r;
                    U[(size_t)row * (NHD * HH) + (size_t)h * HH + e] = f2bf(a[r]);
                }
            }
        }
    } else {
        // ------------- ac (+in-block cb) -------------
        const int idx = bx - 1728;
        const int j0 = (idx % 6) * 64, i0 = ((idx / 6) % 6) * 64;
        const int bh = idx / 36;
        const int b = bh / NHD, h = bh - b * NHD;

        // cb[r] = sum_d qv[(b,i0+r), h*64+d] * br[h*64+d]
        {
            const int r = tid >> 2, seg = tid & 3;
            const unsigned short* qrow = qv + (size_t)(b * SS + i0 + r) * HH + h * 64 + seg * 16;
            const float* brp = br + h * 64 + seg * 16;
            float p = 0.f;
#pragma unroll
            for (int d = 0; d < 16; d++)
                p = fmaf(bf2f(qrow[d]), brp[d], p);
            p += __shfl_xor(p, 1);
            p += __shfl_xor(p, 2);
            if (seg == 0) cbl[r] = p;
        }
        __syncthreads();

        const unsigned short* Ar0 = qu + (size_t)(b * SS + i0 + wr + lrow) * HH + h * 64 + kgrp;
        const unsigned short* Ar1 = Ar0 + 16 * HH;
        const unsigned short* Br0 = kb + (size_t)(b * SS + j0 + wc + lrow) * HH + h * 64 + kgrp;
        const unsigned short* Br1 = Br0 + 16 * HH;

        f32x4 acc00 = {0.f,0.f,0.f,0.f}, acc01 = {0.f,0.f,0.f,0.f};
        f32x4 acc10 = {0.f,0.f,0.f,0.f}, acc11 = {0.f,0.f,0.f,0.f};
#pragma unroll
        for (int k0 = 0; k0 < 64; k0 += 32) {
            const short8 a0 = *(const short8*)(Ar0 + k0);
            const short8 a1 = *(const short8*)(Ar1 + k0);
            const short8 b0 = *(const short8*)(Br0 + k0);
            const short8 b1 = *(const short8*)(Br1 + k0);
            acc00 = __builtin_amdgcn_mfma_f32_16x16x32_bf16(a0, b0, acc00, 0, 0, 0);
            acc01 = __builtin_amdgcn_mfma_f32_16x16x32_bf16(a0, b1, acc01, 0, 0, 0);
            acc10 = __builtin_amdgcn_mfma_f32_16x16x32_bf16(a1, b0, acc10, 0, 0, 0);
            acc11 = __builtin_amdgcn_mfma_f32_16x16x32_bf16(a1, b1, acc11, 0, 0, 0);
        }
#pragma unroll
        for (int tr = 0; tr < 2; tr++) {
#pragma unroll
            for (int tc = 0; tc < 2; tc++) {
                const f32x4 a = (tr == 0) ? ((tc == 0) ? acc00 : acc01)
                                          : ((tc == 0) ? acc10 : acc11);
                const int j = j0 + wc + tc * 16 + lrow;
#pragma unroll
                for (int r = 0; r < 4; r++) {
                    const int ii = i0 + wr + tr * 16 + rbase + r;
                    sc[((size_t)(b * SS + ii) * NHD + h) * SS + j] = a[r] + cbl[ii - i0];
                }
            }
        }
    }
}

// ---------------------------------------------------------------------------
// BD + softmax: one block per (b,i), 256 threads, U in bf16 LDS. [R10-proven
// local optimum: R11 segment-size probe null, R12 occupancy probe negative,
// R9 LDS-reuse lesson applied.]  Softmax writes P as bf16.
// ---------------------------------------------------------------------------
__global__ __launch_bounds__(256) void k_bd(const float* __restrict__ rpe,
                                            const unsigned short* __restrict__ U,
                                            const int* __restrict__ mask,
                                            const float* __restrict__ scin,
                                            unsigned short* __restrict__ Pb) {
    const int i = blockIdx.x;          // 0..383
    const int b = blockIdx.y;          // 0..1
    const int row = b * SS + i;
    const int tid = threadIdx.x;

    __shared__ unsigned short Ul[NHD * HH];   // 18 KB (bf16)
    __shared__ float sc[NHD][392];            // 18.4 KB
    __shared__ float extl[SS];                // 1.5 KB

    const float* plane = scin + (size_t)row * NHD * SS;
    unsigned short* pplane = Pb + (size_t)row * NHD * SS;

    // stage U row (bf16), AC scores plane, mask
    {
        const uint4* Ur = (const uint4*)(U + (size_t)row * NHD * HH);
        uint4* Uld = (uint4*)Ul;
        for (int t = tid; t < NHD * HH / 8; t += 256) Uld[t] = Ur[t];
        for (int t = tid; t < NHD * 96; t += 256) {
            const int h = t / 96, c4 = (t - h * 96) << 2;
            *(float4*)&sc[h][c4] = *(const float4*)&plane[h * SS + c4];
        }
        for (int t = tid; t < SS; t += 256)
            extl[t] = (1.0f - (float)mask[b * SS + t]) * (-1e18f);
    }
    __syncthreads();

    const int wave = tid >> 6;       // 0..3
    const int lane = tid & 63;

    // ---- BD phase: stream rpe[b,i,:,:] once ----
    {
        const int jsub = lane >> 3;      // 0..7
        const int elane = lane & 7;      // 0..7
        const float* rrow = rpe + (size_t)row * SS * HH;

        for (int g = wave; g < 12; g += 4) {
            const int jbase = g * 32 + jsub;
            const float* rp0 = rrow + (size_t)jbase * HH + (elane << 2);
            float acc[4][NHD] = {};
#pragma unroll 2
            for (int ec = 0; ec < 24; ec++) {
                const int eo = ec << 5;                 // 32 e per chunk
                const float4 t0 = *(const float4*)(rp0 + eo);
                const float4 t1 = *(const float4*)(rp0 + eo + 8 * HH);
                const float4 t2 = *(const float4*)(rp0 + eo + 16 * HH);
                const float4 t3 = *(const float4*)(rp0 + eo + 24 * HH);
                const float rb[4][4] = {{t0.x, t0.y, t0.z, t0.w},
                                        {t1.x, t1.y, t1.z, t1.w},
                                        {t2.x, t2.y, t2.z, t2.w},
                                        {t3.x, t3.y, t3.z, t3.w}};
                const int uo = eo + (elane << 2);       // ushort index, 8B aligned
#pragma unroll
                for (int h = 0; h < NHD; h++) {
                    const uint2 w2 = *(const uint2*)&Ul[h * HH + uo];
                    float ub[4];
                    ub[0] = __uint_as_float(w2.x << 16);
                    ub[1] = __uint_as_float(w2.x & 0xffff0000u);
                    ub[2] = __uint_as_float(w2.y << 16);
                    ub[3] = __uint_as_float(w2.y & 0xffff0000u);
#pragma unroll
                    for (int rr = 0; rr < 4; rr++)
#pragma unroll
                        for (int c = 0; c < 4; c++)
                            acc[rr][h] = fmaf(rb[rr][c], ub[c], acc[rr][h]);
                }
            }
#pragma unroll
            for (int rr = 0; rr < 4; rr++)
#pragma unroll
                for (int h = 0; h < NHD; h++) {
                    float a = acc[rr][h];
                    a += __shfl_xor(a, 1);
                    a += __shfl_xor(a, 2);
                    a += __shfl_xor(a, 4);
                    acc[rr][h] = a;
                }
            if (elane == 0) {
#pragma unroll
                for (int rr = 0; rr < 4; rr++) {
                    const int j = jbase + (rr << 3);
#pragma unroll
                    for (int h = 0; h < NHD; h++)
                        sc[h][j] += acc[rr][h];
                }
            }
        }
    }
    __syncthreads();

    // ---- fused softmax (scale + mask), write P (bf16) ----
    {
        for (int h = wave; h < NHD; h += 4) {
            float vbuf[6];
            float m = -1e30f;
#pragma unroll
            for (int t2 = 0; t2 < 6; t2++) {
                vbuf[t2] = sc[h][lane + t2 * 64] * SCALE_F + extl[lane + t2 * 64];
                m = fmaxf(m, vbuf[t2]);
            }
#pragma unroll
            for (int off = 1; off < 64; off <<= 1) m = fmaxf(m, __shfl_xor(m, off));
            float ssum = 0.f;
#pragma unroll
            for (int t2 = 0; t2 < 6; t2++) {
                const float e = __expf(vbuf[t2] - m);
                vbuf[t2] = e;
                ssum += e;
            }
#pragma unroll
            for (int off = 1; off < 64; off <<= 1) ssum += __shfl_xor(ssum, off);
            const float inv = 1.0f / ssum;
#pragma unroll
            for (int t2 = 0; t2 < 6; t2++)
                pplane[h * SS + lane + t2 * 64] = f2bf(vbuf[t2] * inv);
        }
    }
}

// ---------------------------------------------------------------------------
// PV MFMA: ctx_b[b,i,h*64+d] = sum_j P_b[b,i,h,j] * vT_b[(b,h,d),j]  (bf16 out)
// grid (6 itile, 24 bh), block 256, K=384.
// ---------------------------------------------------------------------------
__global__ __launch_bounds__(256) void k_pv(const unsigned short* __restrict__ Pb,
                                            const unsigned short* __restrict__ vTb,
                                            unsigned short* __restrict__ ctxb) {
    const int bh = blockIdx.y;
    const int b = bh / NHD, h = bh - b * NHD;
    const int i0 = blockIdx.x * 64;
    const int tid = threadIdx.x;
    const int wid = tid >> 6, lane = tid & 63;
    const int wr = (wid >> 1) * 32, wc = (wid & 1) * 32;
    const int lrow = lane & 15;
    const int kgrp = (lane >> 4) * 8;

    const unsigned short* Ar0 = Pb + ((size_t)(b * SS + i0 + wr + lrow) * NHD + h) * SS + kgrp;
    const unsigned short* Ar1 = Ar0 + (size_t)16 * NHD * SS;
    const unsigned short* Br0 = vTb + ((size_t)(b * NHD + h) * 64 + wc + lrow) * SS + kgrp;
    const unsigned short* Br1 = Br0 + 16 * SS;

    f32x4 acc00 = {0.f,0.f,0.f,0.f}, acc01 = {0.f,0.f,0.f,0.f};
    f32x4 acc10 = {0.f,0.f,0.f,0.f}, acc11 = {0.f,0.f,0.f,0.f};
#pragma unroll 4
    for (int k0 = 0; k0 < SS; k0 += 32) {
        const short8 a0 = *(const short8*)(Ar0 + k0);
        const short8 a1 = *(const short8*)(Ar1 + k0);
        const short8 b0 = *(const short8*)(Br0 + k0);
        const short8 b1 = *(const short8*)(Br1 + k0);
        acc00 = __builtin_amdgcn_mfma_f32_16x16x32_bf16(a0, b0, acc00, 0, 0, 0);
        acc01 = __builtin_amdgcn_mfma_f32_16x16x32_bf16(a0, b1, acc01, 0, 0, 0);
        acc10 = __builtin_amdgcn_mfma_f32_16x16x32_bf16(a1, b0, acc10, 0, 0, 0);
        acc11 = __builtin_amdgcn_mfma_f32_16x16x32_bf16(a1, b1, acc11, 0, 0, 0);
    }

    const int rbase = (lane >> 4) * 4;
#pragma unroll
    for (int tr = 0; tr < 2; tr++) {
#pragma unroll
        for (int tc = 0; tc < 2; tc++) {
            const f32x4 a = (tr == 0) ? ((tc == 0) ? acc00 : acc01)
                                      : ((tc == 0) ? acc10 : acc11);
            const int d = wc + tc * 16 + lrow;
#pragma unroll
            for (int r = 0; r < 4; r++) {
                const int row = b * SS + i0 + wr + tr * 16 + rbase + r;
                ctxb[(size_t)row * HH + h * 64 + d] = f2bf(a[r]);
            }
        }
    }
}

// ---------------------------------------------------------------------------
// out-proj MFMA (R7-proven, 64x64): lnin = ctx_b @ Wf_b.T + bf + hs
// ---------------------------------------------------------------------------
__global__ __launch_bounds__(256) void k_gemm_out(const unsigned short* __restrict__ A,
                                                  const unsigned short* __restrict__ W,
                                                  const float* __restrict__ bias,
                                                  const float* __restrict__ addsrc,
                                                  float* __restrict__ C) {
    const int tid = threadIdx.x;
    const int wid = tid >> 6, lane = tid & 63;
    const int i0 = blockIdx.y * 64, o0 = blockIdx.x * 64;
    const int wr = (wid >> 1) * 32, wc = (wid & 1) * 32;
    const int lrow = lane & 15;
    const int kgrp = (lane >> 4) * 8;

    const unsigned short* Ar0 = A + (size_t)(i0 + wr + lrow) * HH + kgrp;
    const unsigned short* Ar1 = Ar0 + 16 * HH;
    const unsigned short* Wr0 = W + (size_t)(o0 + wc + lrow) * HH + kgrp;
    const unsigned short* Wr1 = Wr0 + 16 * HH;

    f32x4 acc00 = {0.f,0.f,0.f,0.f}, acc01 = {0.f,0.f,0.f,0.f};
    f32x4 acc10 = {0.f,0.f,0.f,0.f}, acc11 = {0.f,0.f,0.f,0.f};
#pragma unroll 4
    for (int k0 = 0; k0 < HH; k0 += 32) {
        const short8 a0 = *(const short8*)(Ar0 + k0);
        const short8 a1 = *(const short8*)(Ar1 + k0);
        const short8 b0 = *(const short8*)(Wr0 + k0);
        const short8 b1 = *(const short8*)(Wr1 + k0);
        acc00 = __builtin_amdgcn_mfma_f32_16x16x32_bf16(a0, b0, acc00, 0, 0, 0);
        acc01 = __builtin_amdgcn_mfma_f32_16x16x32_bf16(a0, b1, acc01, 0, 0, 0);
        acc10 = __builtin_amdgcn_mfma_f32_16x16x32_bf16(a1, b0, acc10, 0, 0, 0);
        acc11 = __builtin_amdgcn_mfma_f32_16x16x32_bf16(a1, b1, acc11, 0, 0, 0);
    }

    const int rbase = (lane >> 4) * 4;
#pragma unroll
    for (int tr = 0; tr < 2; tr++) {
#pragma unroll
        for (int tc = 0; tc < 2; tc++) {
            const f32x4 a = (tr == 0) ? ((tc == 0) ? acc00 : acc01)
                                      : ((tc == 0) ? acc10 : acc11);
            const int col = o0 + wc + tc * 16 + lrow;
            const float bv = bias[col];
#pragma unroll
            for (int r = 0; r < 4; r++) {
                const int row = i0 + wr + tr * 16 + rbase + r;
                C[(size_t)row * HH + col] = a[r] + bv + addsrc[(size_t)row * HH + col];
            }
        }
    }
}

// ---------------------------------------------------------------------------
// LayerNorm over last dim (768) per row
// ---------------------------------------------------------------------------
__global__ __launch_bounds__(256) void k_ln(const float* __restrict__ x,
                                            const float* __restrict__ g,
                                            const float* __restrict__ bta,
                                            float* __restrict__ o) {
    const int row = blockIdx.x;
    const int tid = threadIdx.x;
    const float* xr = x + (size_t)row * HH;
    __shared__ float red[4];
    const float v0 = xr[tid], v1 = xr[tid + 256], v2 = xr[tid + 512];
    float s = v0 + v1 + v2;
#pragma unroll
    for (int off = 1; off < 64; off <<= 1) s += __shfl_xor(s, off);
    if ((tid & 63) == 0) red[tid >> 6] = s;
    __syncthreads();
    const float mean = (red[0] + red[1] + red[2] + red[3]) * (1.0f / 768.0f);
    const float d0 = v0 - mean, d1 = v1 - mean, d2 = v2 - mean;
    float sq = d0 * d0 + d1 * d1 + d2 * d2;
#pragma unroll
    for (int off = 1; off < 64; off <<= 1) sq += __shfl_xor(sq, off);
    __syncthreads();
    if ((tid & 63) == 0) red[tid >> 6] = sq;
    __syncthreads();
    const float var = (red[0] + red[1] + red[2] + red[3]) * (1.0f / 768.0f);
    const float inv = rsqrtf(var + 1e-6f);
    o[(size_t)row * HH + tid]       = d0 * inv * g[tid]       + bta[tid];
    o[(size_t)row * HH + tid + 256] = d1 * inv * g[tid + 256] + bta[tid + 256];
    o[(size_t)row * HH + tid + 512] = d2 * inv * g[tid + 512] + bta[tid + 512];
}

// ---------------------------------------------------------------------------
extern "C" void kernel_launch(void* const* d_in, const int* in_sizes, int n_in,
                              void* d_out, int out_size, void* d_ws, size_t ws_size,
                              hipStream_t stream) {
    (void)in_sizes; (void)n_in; (void)out_size; (void)ws_size;
    const float* hs   = (const float*)d_in[0];
    const int*   mask = (const int*)d_in[1];
    const float* rpe  = (const float*)d_in[2];
    const float* Wq = (const float*)d_in[3];  const float* bq = (const float*)d_in[4];
    const float* Wk = (const float*)d_in[5];  const float* bk = (const float*)d_in[6];
    const float* Wv = (const float*)d_in[7];  const float* bv = (const float*)d_in[8];
    const float* Wr = (const float*)d_in[9];  const float* br = (const float*)d_in[10];
    const float* u  = (const float*)d_in[11]; const float* v  = (const float*)d_in[12];
    const float* Wf = (const float*)d_in[13]; const float* bf = (const float*)d_in[14];
    const float* lng = (const float*)d_in[15]; const float* lnb = (const float*)d_in[16];
    float* out = (float*)d_out;

    const size_t MAT = (size_t)ROWS * HH;              // 589824
    float* wsf     = (float*)d_ws;
    float* lnin_ws = wsf;                              // fp32 region
    float* sc_ws   = lnin_ws + MAT;                    // ROWS*NHD*SS f32
    unsigned short* U_ws  = (unsigned short*)(sc_ws + (size_t)ROWS * NHD * SS);
    unsigned short* hs_b  = U_ws + (size_t)ROWS * NHD * HH;
    unsigned short* Wq_b  = hs_b + MAT;
    unsigned short* Wk_b  = Wq_b + MAT;
    unsigned short* Wv_b  = Wk_b + MAT;
    unsigned short* Wf_b  = Wv_b + MAT;
    unsigned short* WrT_b = Wf_b + MAT;
    unsigned short* qu_b  = WrT_b + MAT;
    unsigned short* qv_b  = qu_b + MAT;
    unsigned short* k_b   = qv_b + MAT;
    unsigned short* vT_b  = k_b + MAT;
    unsigned short* ctx_b = vT_b + MAT;
    unsigned short* P_b   = ctx_b + MAT;               // ROWS*NHD*SS bf16

    k_tobf<<<dim3(576, 6), 256, 0, stream>>>(hs, Wq, Wk, Wv, Wf, Wr,
                                             hs_b, Wq_b, Wk_b, Wv_b, Wf_b, WrT_b);
    k_gemm_qkv<<<dim3(12, 12, 3), 256, 0, stream>>>(hs_b, Wq_b, bq, Wk_b, bk, Wv_b, bv,
                                                    u, v, qu_b, qv_b, k_b, vT_b);
    k_mid<<<dim3(2592), 256, 0, stream>>>(qv_b, WrT_b, qu_b, k_b, br, U_ws, sc_ws);
    k_bd<<<dim3(SS, BB), 256, 0, stream>>>(rpe, U_ws, mask, sc_ws, P_b);
    k_pv<<<dim3(6, 24), 256, 0, stream>>>(P_b, vT_b, ctx_b);
    k_gemm_out<<<dim3(12, 12), 256, 0, stream>>>(ctx_b, Wf_b, bf, hs, lnin_ws);
    k_ln<<<dim3(768), 256, 0, stream>>>(lnin_ws, lng, lnb, out);
}